// Round 2
// baseline (150.563 us; speedup 1.0000x reference)
//
#include <hip/hip_runtime.h>

// Problem constants (static per reference setup_inputs)
#define BB     16
#define HH     128
#define WW     8192
#define N_MAXC 128
#define W_OUTC 6271
#define SEP_CLASS 2.0f

// d_out layout (all float32): x_new [B*H*W_OUT] | xi_new [B*N_MAX*2] | xl_new [B*W_OUT]
#define X_ELEMS (BB * HH * W_OUTC)
#define XI_OFF  (X_ELEMS)
#define XL_OFF  (X_ELEMS + BB * N_MAXC * 2)

#define MAP_BYTES ((size_t)(BB * W_OUTC) * sizeof(int))

// ---------------- shared helpers ----------------

// Matches reference: w_valid = (i<Nb) ? max(e0-s0,0) : 0; csum = cumsum;
// sn = csum - w_valid + i; en = csum + i.
__device__ __forceinline__ void compute_scan(const int* __restrict__ xi, int b, int Nb,
                                             int* s_s0, int* s_e0, int* s_sn, int* s_en,
                                             int tid) {
    if (tid < N_MAXC) {
        s_s0[tid] = xi[(b * N_MAXC + tid) * 2 + 0];
        s_e0[tid] = xi[(b * N_MAXC + tid) * 2 + 1];
    }
    __syncthreads();
    if (tid == 0) {
        int c = 0;
        for (int i = 0; i < N_MAXC; ++i) {
            int w = s_e0[i] - s_s0[i];
            if (w < 0) w = 0;
            int wv = (i < Nb) ? w : 0;
            c += wv;
            s_sn[i] = c - wv + i;
            s_en[i] = c + i;
        }
    }
    __syncthreads();
}

// Column classification: >=0 src index | -1 separator | -2 zero.
__device__ __forceinline__ int map_col(int t, int Nb,
                                       const int* s_s0, const int* s_e0,
                                       const int* s_sn, const int* s_en) {
    // i = #{valid j : en[j] <= t}; en strictly increasing on [0,Nb)
    int lo = 0, hi = Nb;
    while (lo < hi) {
        int mid = (lo + hi) >> 1;
        if (s_en[mid] <= t) lo = mid + 1; else hi = mid;
    }
    int i = lo;                                   // in [0, Nb]
    int ic = (i < N_MAXC - 1) ? i : (N_MAXC - 1);
    if (i < Nb) {
        int sn = s_sn[ic], en = s_en[ic];
        if (t >= sn && en > sn && s_e0[ic] > s_s0[ic]) {
            int src = s_s0[ic] + (t - sn);
            src = src < 0 ? 0 : (src > WW - 1 ? WW - 1 : src);
            return src;
        }
    }
    if (i >= 1) {
        int en_prev = s_en[i - 1];
        if (t == en_prev && (i - 1) < (Nb - 1) && en_prev < WW) return -1;
    }
    return -2;
}

// ---------------- kernel A: map + xi_new + xl_new ----------------
// Grid (BB, 7): block (b, tile) owns 1024 output columns of batch b.
#define META_TCOLS 1024

__global__ __launch_bounds__(256) void tb_meta_kernel(const int* __restrict__ xi,
                                                      const int* __restrict__ Nv,
                                                      const int* __restrict__ xl,
                                                      float* __restrict__ out,
                                                      int* __restrict__ map) {
    __shared__ int s_s0[N_MAXC], s_e0[N_MAXC], s_sn[N_MAXC], s_en[N_MAXC];
    const int b   = blockIdx.x;
    const int tid = threadIdx.x;
    const int Nb  = Nv[b];
    compute_scan(xi, b, Nb, s_s0, s_e0, s_sn, s_en, tid);

    if (blockIdx.y == 0 && tid < N_MAXC) {
        const bool valid = tid < Nb;
        out[XI_OFF + (b * N_MAXC + tid) * 2 + 0] = valid ? (float)s_sn[tid] : 0.0f;
        out[XI_OFF + (b * N_MAXC + tid) * 2 + 1] = valid ? (float)s_en[tid] : 0.0f;
    }
    const int t_lo = blockIdx.y * META_TCOLS;
    const int t_hi = (t_lo + META_TCOLS < W_OUTC) ? t_lo + META_TCOLS : W_OUTC;
    for (int t = t_lo + tid; t < t_hi; t += blockDim.x) {
        int m = map_col(t, Nb, s_s0, s_e0, s_sn, s_en);
        if (map) map[b * W_OUTC + t] = m;
        float v;
        if (m >= 0)       v = (float)xl[b * WW + m];
        else if (m == -1) v = SEP_CLASS;
        else              v = 0.0f;
        out[XL_OFF + b * W_OUTC + t] = v;
    }
}

// ---------------- kernel B (primary): flat float4 gather ----------------
// Each thread handles 16B-aligned chunks of 4 consecutive flat x_new elements.
__global__ __launch_bounds__(256) void tb_gather_flat(const float* __restrict__ x,
                                                      const int* __restrict__ map,
                                                      const float* __restrict__ sep_param,
                                                      float* __restrict__ out) {
    const float sep = sep_param[0];
    const unsigned nChunks = (unsigned)(X_ELEMS / 4);   // divisible: 12,843,008 / 4
    const unsigned stride  = gridDim.x * blockDim.x;
    for (unsigned c = blockIdx.x * blockDim.x + threadIdx.x; c < nChunks; c += stride) {
        const unsigned flat = c * 4u;
        const unsigned bh   = flat / W_OUTC;            // magic-mul divide (constant)
        const unsigned t0   = flat - bh * W_OUTC;
        float4 v;
        float* vv = (float*)&v;
        #pragma unroll
        for (int k = 0; k < 4; ++k) {
            unsigned tk  = t0 + (unsigned)k;
            unsigned bh2 = bh;
            if (tk >= W_OUTC) { tk -= W_OUTC; bh2 = bh + 1; }   // row wrap (<=1 per chunk)
            const unsigned b2 = bh2 >> 7;                        // /HH
            const int m = map[b2 * W_OUTC + tk];
            float val;
            if (m >= 0)       val = x[((size_t)bh2 << 13) + (unsigned)m];  // bh2*WW + m
            else if (m == -1) val = sep;
            else              val = 0.0f;
            vv[k] = val;
        }
        ((float4*)out)[c] = v;
    }
}

// ---------------- kernel B (fallback, no ws): tiled gather ----------------
#define TILE   512
#define HCHUNK 32

__global__ __launch_bounds__(256) void tb_gather_tiled(const float* __restrict__ x,
                                                       const int* __restrict__ xi,
                                                       const int* __restrict__ Nv,
                                                       const float* __restrict__ sep_param,
                                                       float* __restrict__ out) {
    __shared__ int s_s0[N_MAXC], s_e0[N_MAXC], s_sn[N_MAXC], s_en[N_MAXC];
    __shared__ int s_map[TILE];
    const int b   = blockIdx.z;
    const int h0  = blockIdx.y * HCHUNK;
    const int t0  = blockIdx.x * TILE;
    const int tid = threadIdx.x;
    const int Nb  = Nv[b];
    compute_scan(xi, b, Nb, s_s0, s_e0, s_sn, s_en, tid);

    for (int j = tid; j < TILE; j += blockDim.x) {
        int t = t0 + j;
        s_map[j] = (t < W_OUTC) ? map_col(t, Nb, s_s0, s_e0, s_sn, s_en) : -2;
    }
    __syncthreads();

    const float sep = sep_param[0];
    const float* xb = x   + (size_t)b * HH * WW;
    float*       ob = out + (size_t)b * HH * W_OUTC;

    for (int r = 0; r < HCHUNK; ++r) {
        const int h = h0 + r;
        const float* xr   = xb + (size_t)h * WW;
        float*       orow = ob + (size_t)h * W_OUTC;
        for (int j = tid; j < TILE; j += blockDim.x) {
            int t = t0 + j;
            if (t < W_OUTC) {
                int m = s_map[j];
                orow[t] = (m >= 0) ? xr[m] : ((m == -1) ? sep : 0.0f);
            }
        }
    }
}

extern "C" void kernel_launch(void* const* d_in, const int* in_sizes, int n_in,
                              void* d_out, int out_size, void* d_ws, size_t ws_size,
                              hipStream_t stream) {
    const float* x   = (const float*)d_in[0];
    const int*   xi  = (const int*)  d_in[1];
    const int*   Nv  = (const int*)  d_in[2];
    const int*   xl  = (const int*)  d_in[3];
    const float* sep = (const float*)d_in[4];
    float*       out = (float*)d_out;

    const bool use_ws = (ws_size >= MAP_BYTES) && (d_ws != nullptr);
    int* map = use_ws ? (int*)d_ws : nullptr;

    tb_meta_kernel<<<dim3(BB, 7), dim3(256), 0, stream>>>(xi, Nv, xl, out, map);

    if (use_ws) {
        tb_gather_flat<<<dim3(2048), dim3(256), 0, stream>>>(x, map, sep, out);
    } else {
        dim3 grid((W_OUTC + TILE - 1) / TILE, HH / HCHUNK, BB);
        tb_gather_tiled<<<grid, dim3(256), 0, stream>>>(x, xi, Nv, sep, out);
    }
}